// Round 13
// baseline (486.845 us; speedup 1.0000x reference)
//
#include <hip/hip_runtime.h>

// ImprovedGraphSAGE: 4x SAGEConv(aggr='lstm') on MI355X.
// N=20000 nodes, DEG=16, F_IN=HID=128, OUT=64, E=320000.
//
// R13 = R12 + within-step x-part pipelining:
//   per row-tile rt: h-MFMA(cur) ; x-part(nxt = rt+1) ; activations(cur) —
//   the independent x-part MFMA/ds_read cluster co-schedules with the
//   trans-heavy activation burst (acc ping-pong accA/accB, +16 regs, stays
//   in the 2-wave/SIMD register band). t=0 and t=15 peeled so the 14 hot
//   iterations are branch-free. Everything else identical to R12
//   (pre-scaled weights, coalesced x staging, lgkm-only barriers).

#define N_NODES 20000
#define DEG 16
#define NPB 80   // nodes per block
#define RT 5     // row tiles (16 rows each)

typedef __bf16 bf16x8 __attribute__((ext_vector_type(8)));
typedef float f32x4 __attribute__((ext_vector_type(4)));

__device__ inline unsigned short f2bf(float f) {
  unsigned u = __builtin_bit_cast(unsigned, f);
  u += 0x7fffu + ((u >> 16) & 1u);
  return (unsigned short)(u >> 16);
}
__device__ inline float fexp2(float x) {
#if __has_builtin(__builtin_amdgcn_exp2f)
  return __builtin_amdgcn_exp2f(x);
#else
  return exp2f(x);
#endif
}
__device__ inline float frcp(float x) {
#if __has_builtin(__builtin_amdgcn_rcpf)
  return __builtin_amdgcn_rcpf(x);
#else
  return 1.f / x;
#endif
}

// LDS-only barrier: flush LDS ops, sync execution, leave global loads in
// flight (no vmcnt drain); consumers get compiler-counted vmcnt waits.
__device__ inline void barrier_lds() {
  asm volatile("s_waitcnt lgkmcnt(0)\n\ts_barrier" ::: "memory");
}

// ---------------------------------------------------------------------------
// prep: weights fp32 -> bf16 with PER-GATE ARGUMENT PRE-SCALING:
//   gates i,f,o: scale by -log2(e)  = -1.44269504
//   gate  g    : scale by -2log2(e) = -2.88539008
// so sigm(x) = rcp(1+exp2(W'x)) and tanh(g) = 2*rcp(1+exp2(W'x)) - 1 need no
// in-kernel multiply. bsum = scale*(bih+bhh).
// ---------------------------------------------------------------------------
__global__ __launch_bounds__(256) void prep_weights(
    const float* __restrict__ Wih, const float* __restrict__ Whh,
    const float* __restrict__ bih, const float* __restrict__ bhh,
    unsigned short* __restrict__ WihB, unsigned short* __restrict__ WhhB,
    float* __restrict__ bsum) {
  int tid = blockIdx.x * 256 + threadIdx.x;  // 0..65535 float4 tasks
  int gate = ((tid >> 5) & 511) >> 7;
  float s = (gate == 2) ? -2.88539008f : -1.44269504f;
  float4 a = *(const float4*)(Wih + tid * 4);
  ushort4 o;
  o.x = f2bf(a.x * s); o.y = f2bf(a.y * s); o.z = f2bf(a.z * s); o.w = f2bf(a.w * s);
  *(ushort4*)(WihB + tid * 4) = o;
  float4 b = *(const float4*)(Whh + tid * 4);
  ushort4 p;
  p.x = f2bf(b.x * s); p.y = f2bf(b.y * s); p.z = f2bf(b.z * s); p.w = f2bf(b.w * s);
  *(ushort4*)(WhhB + tid * 4) = p;
  if (tid < 2048) {
    int g2 = (tid & 511) >> 7;
    float s2 = (g2 == 2) ? -2.88539008f : -1.44269504f;
    bsum[tid] = s2 * (bih[tid] + bhh[tid]);
  }
}

// ---------------------------------------------------------------------------
// cast: xbf = bf16(x)
// ---------------------------------------------------------------------------
__global__ __launch_bounds__(256) void cast_bf(
    const float* __restrict__ x, unsigned short* __restrict__ xb) {
  int tid = blockIdx.x * 256 + threadIdx.x;
  float4 v = *(const float4*)(x + tid * 4);
  ushort4 o;
  o.x = f2bf(v.x); o.y = f2bf(v.y); o.z = f2bf(v.z); o.w = f2bf(v.w);
  *(ushort4*)(xb + tid * 4) = o;
}

// ---------------------------------------------------------------------------
// lstm_fused: WG = 80 nodes, 8 waves; wave w owns gate-cols {g*128 + w*16+l15}.
// ---------------------------------------------------------------------------
__global__ __launch_bounds__(512, 2) void lstm_fused(
    const unsigned short* __restrict__ xbf,   // [N][128] bf16
    const int* __restrict__ src,              // [E]
    const unsigned short* __restrict__ WihB,  // [512][128] bf16 (layer slice)
    const unsigned short* __restrict__ WhhB,  // [512][128] bf16
    const float* __restrict__ bsum,           // [512]
    float* __restrict__ agg) {                // [N,128] fp32
  __shared__ __align__(16) unsigned char xsb[2][NPB * 256];   // x dbuf (40KB)
  __shared__ __align__(16) unsigned char hbuf[2][NPB * 256];  // h dbuf (40KB)
  __shared__ __align__(16) int idx_s[NPB * DEG];              // [t*80 + node]
  const int tid = threadIdx.x;
  const int lane = tid & 63, w = tid >> 6;
  const int l15 = lane & 15, l4 = lane >> 4;
  const int node0 = blockIdx.x * NPB;
  const int colb = w * 16 + l15;  // this wave-lane's output column (per gate)

  // edge indices: task = node*16 + t  ->  idx_s[t*80 + node]
#pragma unroll
  for (int i = 0; i < 3; ++i) {
    int task = tid + i * 512;
    if (task < NPB * DEG) {
      int node = task >> 4, t = task & 15;
      idx_s[t * NPB + node] = src[node0 * DEG + task];
    }
  }

  // weight B-fragments (bf16, pre-scaled): B[k][n] = W[gate*128+colb][k]
  bf16x8 bwx[4][4], bwh[4][4];
  float bs[4];
#pragma unroll
  for (int g = 0; g < 4; ++g) {
#pragma unroll
    for (int kt = 0; kt < 4; ++kt) {
      bwx[g][kt] = *(const bf16x8*)(WihB + (g * 128 + colb) * 128 + kt * 32 + l4 * 8);
      bwh[g][kt] = *(const bf16x8*)(WhhB + (g * 128 + colb) * 128 + kt * 32 + l4 * 8);
    }
    bs[g] = bsum[g * 128 + colb];
  }
  barrier_lds();  // idx_s visible

  // staging tasks: task = row*16 + chunk; LDS physical chunk p holds logical
  // chunk p ^ (row&7)  (matches the XOR-swizzled read below).
  const int task0 = tid, task1 = tid + 512;
  const int row0s = task0 >> 4, ch0 = task0 & 15;
  const int row1s = task1 >> 4, ch1 = task1 & 15;
  const int task2 = tid + 1024;
  const bool p2 = task2 < NPB * 16;
  const int row2s = task2 >> 4, ch2 = task2 & 15;

  // prologue: stage x rows for t=0
  {
    uint4 v0 = *(const uint4*)(xbf + idx_s[row0s] * 128 + (ch0 ^ (row0s & 7)) * 8);
    uint4 v1 = *(const uint4*)(xbf + idx_s[row1s] * 128 + (ch1 ^ (row1s & 7)) * 8);
    *(uint4*)(&xsb[0][row0s * 256 + ch0 * 16]) = v0;
    *(uint4*)(&xsb[0][row1s * 256 + ch1 * 16]) = v1;
    if (p2) {
      uint4 v2 = *(const uint4*)(xbf + idx_s[row2s] * 128 + (ch2 ^ (row2s & 7)) * 8);
      *(uint4*)(&xsb[0][row2s * 256 + ch2 * 16]) = v2;
    }
  }
  barrier_lds();  // xsb[0] ready

  float c[RT][4];
#pragma unroll
  for (int rt = 0; rt < RT; ++rt)
#pragma unroll
    for (int r = 0; r < 4; ++r) c[rt][r] = 0.f;

  f32x4 accA[4], accB[4];  // ping-pong accumulators (x-part pipelined per rt)

  // x-part: acc = bias; acc += x_t[rt]@Wih  (reads xrb, XOR on FULL offset)
  auto xpart = [&](f32x4* acc, const unsigned char* xrb, int rtn) {
#pragma unroll
    for (int g = 0; g < 4; ++g) acc[g] = (f32x4){bs[g], bs[g], bs[g], bs[g]};
    const int m = rtn * 16 + l15;
#pragma unroll
    for (int kt = 0; kt < 4; ++kt) {
      int byte = (m * 256 + kt * 64 + l4 * 16) ^ ((m & 7) << 4);
      bf16x8 a = *(const bf16x8*)(xrb + byte);
#pragma unroll
      for (int g = 0; g < 4; ++g)
        acc[g] = __builtin_amdgcn_mfma_f32_16x16x32_bf16(a, bwx[g][kt], acc[g], 0, 0, 0);
    }
  };
  // h-part: acc += h_{t-1}[rt]@Whh
  auto hpart = [&](f32x4* acc, const unsigned char* hb, int rtn) {
    const int m = rtn * 16 + l15;
#pragma unroll
    for (int kt = 0; kt < 4; ++kt) {
      int byte = (m * 256 + kt * 64 + l4 * 16) ^ ((m & 7) << 4);
      bf16x8 a = *(const bf16x8*)(hb + byte);
#pragma unroll
      for (int g = 0; g < 4; ++g)
        acc[g] = __builtin_amdgcn_mfma_f32_16x16x32_bf16(a, bwh[g][kt], acc[g], 0, 0, 0);
    }
  };

  // one LSTM step; first/last are literal at each call site (constant-fold)
  auto step = [&](int t, bool first, bool last) {
    const unsigned char* xrb = xsb[t & 1];
    const unsigned char* hb = hbuf[(t + 1) & 1];  // == (t-1)&1
    unsigned char* hw = hbuf[t & 1];

    // issue next step's x gather into regs (T14: write after compute)
    uint4 xstg0, xstg1, xstg2;
    if (!last) {
      const int tb = (t + 1) * NPB;
      xstg0 = *(const uint4*)(xbf + idx_s[tb + row0s] * 128 + (ch0 ^ (row0s & 7)) * 8);
      xstg1 = *(const uint4*)(xbf + idx_s[tb + row1s] * 128 + (ch1 ^ (row1s & 7)) * 8);
      if (p2)
        xstg2 = *(const uint4*)(xbf + idx_s[tb + row2s] * 128 + (ch2 ^ (row2s & 7)) * 8);
    }

    xpart(accA, xrb, 0);  // rt=0 x-part prologue

#pragma unroll
    for (int rt = 0; rt < RT; ++rt) {
      f32x4* cur = (rt & 1) ? accB : accA;
      f32x4* nxt = (rt & 1) ? accA : accB;
      if (!first) hpart(cur, hb, rt);
      if (rt + 1 < RT) xpart(nxt, xrb, rt + 1);  // co-schedules with act below

      // gates + state update (weights pre-scaled; see prep_weights)
#pragma unroll
      for (int r = 0; r < 4; ++r) {
        float ig = frcp(1.f + fexp2(cur[0][r]));
        float fg = frcp(1.f + fexp2(cur[1][r]));
        float gg = 2.f * frcp(1.f + fexp2(cur[2][r])) - 1.f;
        float og = frcp(1.f + fexp2(cur[3][r]));
        float cn = fg * c[rt][r] + ig * gg;
        c[rt][r] = cn;
        float th = 2.f * frcp(1.f + fexp2(-2.88539008f * cn)) - 1.f;
        float hv = og * th;
        int mm = rt * 16 + l4 * 4 + r;
        if (!last) {
          int byte = (mm * 256 + colb * 2) ^ ((mm & 7) << 4);
          *(__bf16*)(hw + byte) = (__bf16)hv;
        } else {
          agg[(node0 + mm) * 128 + colb] = hv;
        }
      }
    }

    if (!last) {
      // write staged x for t+1 (linear; src was pre-swizzled)
      unsigned char* xw = xsb[(t + 1) & 1];
      *(uint4*)(&xw[row0s * 256 + ch0 * 16]) = xstg0;
      *(uint4*)(&xw[row1s * 256 + ch1 * 16]) = xstg1;
      if (p2) *(uint4*)(&xw[row2s * 256 + ch2 * 16]) = xstg2;
      barrier_lds();  // h_t and x_{t+1} visible; loads keep flying
    }
  };

  step(0, true, false);  // peeled: no h-part
#pragma unroll 2
  for (int t = 1; t < 15; ++t) step(t, false, false);  // branch-free hot loop
  step(15, false, true);  // peeled: agg-store epilogue, no staging/barrier
}

// ---------------------------------------------------------------------------
// gemm_out: out[N,NOUT] = agg@Wl.T + bl + x@Wr.T (+resid) (+relu)
// One K=256 GEMM with A = [agg | x], B = [Wl | Wr]. Optionally dual-writes
// bf16 copy (next layer's gather source).
// ---------------------------------------------------------------------------
__global__ __launch_bounds__(256) void gemm_out(
    const float* __restrict__ A1,   // agg [N,128]
    const float* __restrict__ A2,   // x   [N,128]
    const float* __restrict__ Wl, const float* __restrict__ bl,
    const float* __restrict__ Wr,
    const float* __restrict__ resid,    // nullptr or [N,128]
    float* __restrict__ out,
    unsigned short* __restrict__ outbf,  // nullptr or [N,128] bf16
    int NOUT, int do_relu, int Nrows) {
  __shared__ __align__(16) unsigned char As[64 * 512];  // [64 rows][256 bf16], swizzled
  const int tid = threadIdx.x;
  const int lane = tid & 63, w = tid >> 6;
  const int l15 = lane & 15, l4 = lane >> 4;
  const int row0 = blockIdx.x * 64;

#pragma unroll
  for (int i = 0; i < 16; ++i) {
    int flat = i * 1024 + tid * 4;  // 0..16383
    int r = flat >> 8, c = flat & 255;
    int grow = row0 + r;
    float4 v;
    if (grow < Nrows)
      v = (c < 128) ? *(const float4*)(A1 + grow * 128 + c)
                    : *(const float4*)(A2 + grow * 128 + (c - 128));
    else
      v = make_float4(0.f, 0.f, 0.f, 0.f);
    ushort4 b;
    b.x = f2bf(v.x); b.y = f2bf(v.y); b.z = f2bf(v.z); b.w = f2bf(v.w);
    int byte = (r * 512 + c * 2) ^ ((r & 7) << 4);
    *(ushort4*)(As + byte) = b;
  }
  __syncthreads();

  const int colg = blockIdx.y * 64 + w * 16 + l15;
  bf16x8 bw[8];
#pragma unroll
  for (int kt = 0; kt < 8; ++kt) {
    const float* bp = (kt < 4) ? (Wl + colg * 128 + kt * 32 + l4 * 8)
                               : (Wr + colg * 128 + (kt - 4) * 32 + l4 * 8);
    float4 a = *(const float4*)bp;
    float4 b = *(const float4*)(bp + 4);
    bf16x8 v;
    v[0] = (__bf16)a.x; v[1] = (__bf16)a.y; v[2] = (__bf16)a.z; v[3] = (__bf16)a.w;
    v[4] = (__bf16)b.x; v[5] = (__bf16)b.y; v[6] = (__bf16)b.z; v[7] = (__bf16)b.w;
    bw[kt] = v;
  }

  f32x4 acc[4];
#pragma unroll
  for (int rt = 0; rt < 4; ++rt) acc[rt] = (f32x4){0.f, 0.f, 0.f, 0.f};

#pragma unroll
  for (int kt = 0; kt < 8; ++kt) {
#pragma unroll
    for (int rt = 0; rt < 4; ++rt) {
      int m = rt * 16 + l15;
      int byte = (m * 512 + kt * 64 + l4 * 16) ^ ((m & 7) << 4);
      bf16x8 af = *(const bf16x8*)(As + byte);
      acc[rt] = __builtin_amdgcn_mfma_f32_16x16x32_bf16(af, bw[kt], acc[rt], 0, 0, 0);
    }
  }

  const float bias = bl[colg];
#pragma unroll
  for (int rt = 0; rt < 4; ++rt)
#pragma unroll
    for (int r = 0; r < 4; ++r) {
      int grow = row0 + rt * 16 + l4 * 4 + r;
      if (grow < Nrows) {
        float v = acc[rt][r] + bias;
        if (resid) v += resid[grow * 128 + colg];
        if (do_relu) v = fmaxf(v, 0.f);
        out[grow * NOUT + colg] = v;
        if (outbf) outbf[grow * 128 + colg] = f2bf(v);
      }
    }
}

// ---------------------------------------------------------------------------
extern "C" void kernel_launch(void* const* d_in, const int* in_sizes, int n_in,
                              void* d_out, int out_size, void* d_ws, size_t ws_size,
                              hipStream_t stream) {
  const float* X = (const float*)d_in[0];
  const int* src = (const int*)d_in[1];  // edge_index[0] = first E ints
  const float* Wih = (const float*)d_in[2];
  const float* Whh = (const float*)d_in[3];
  const float* bih = (const float*)d_in[4];
  const float* bhh = (const float*)d_in[5];
  const float* Wl123 = (const float*)d_in[6];
  const float* bl123 = (const float*)d_in[7];
  const float* Wr123 = (const float*)d_in[8];
  const float* Wl4 = (const float*)d_in[9];
  const float* bl4 = (const float*)d_in[10];
  const float* Wr4 = (const float*)d_in[11];
  float* out = (float*)d_out;

  char* ws = (char*)d_ws;
  unsigned short* xbf = (unsigned short*)ws;                 // 5.12 MB
  float* agg = (float*)(ws + 5120000);                       // 10.24 MB
  float* xb0 = (float*)(ws + 15360000);                      // 10.24 MB
  float* xb1 = (float*)(ws + 25600000);                      // 10.24 MB
  unsigned short* WihB = (unsigned short*)(ws + 35840000);   // 0.52 MB
  unsigned short* WhhB = (unsigned short*)(ws + 36364288);   // 0.52 MB
  float* bsumW = (float*)(ws + 36888576);                    // 8 KB

  prep_weights<<<dim3(256), 256, 0, stream>>>(Wih, Whh, bih, bhh, WihB, WhhB, bsumW);
  cast_bf<<<dim3(2500), 256, 0, stream>>>(X, xbf);

  const float* xcur = X;
  for (int L = 0; L < 4; ++L) {
    lstm_fused<<<dim3(250), 512, 0, stream>>>(xbf, src, WihB + L * 65536,
                                              WhhB + L * 65536, bsumW + L * 512, agg);
    if (L < 3) {
      float* nxt = (L & 1) ? xb1 : xb0;
      gemm_out<<<dim3(313, 2), 256, 0, stream>>>(agg, xcur, Wl123 + L * 16384,
                                                 bl123 + L * 128, Wr123 + L * 16384,
                                                 (L >= 1) ? xcur : nullptr, nxt, xbf,
                                                 128, 1, N_NODES);
      xcur = nxt;
    } else {
      gemm_out<<<dim3(313, 1), 256, 0, stream>>>(agg, xcur, Wl4, bl4, Wr4, nullptr, out,
                                                 nullptr, 64, 0, N_NODES);
    }
  }
}

// Round 14
// 451.007 us; speedup vs baseline: 1.0795x; 1.0795x over previous
//
#include <hip/hip_runtime.h>

// ImprovedGraphSAGE: 4x SAGEConv(aggr='lstm') on MI355X.
// N=20000 nodes, DEG=16, F_IN=HID=128, OUT=64, E=320000.
//
// R14 = R12 (best: 250 blocks x 80 nodes, pre-scaled weights, coalesced x
// staging, per-rt step, lgkm-only barriers) with the LDS swizzle upgraded
// from f(m)=m&7 to f(m)=(m^(m>>3))&7: the old mask made h-write rows m and
// m+8 share a bank-set (4-way conflict, ~7.5% of CU cycles, the constant
// 5.03M SQ_LDS_BANK_CONFLICT seen in every round). The new f gives the write
// burst rows {r,r+4,r+8,r+12} four distinct bank shifts -> 2 lanes/bank
// (free), while read bank-quad occupancy stays at the structural minimum.
// Same involution applied at all four sites (stage-src, x-read, h-read,
// h-write) per rule #21. R13's ping-pong restructure (regression) reverted.

#define N_NODES 20000
#define DEG 16
#define NPB 80   // nodes per block
#define RT 5     // row tiles (16 rows each)
#define SWZ(m) ((((m) ^ ((m) >> 3)) & 7))

typedef __bf16 bf16x8 __attribute__((ext_vector_type(8)));
typedef float f32x4 __attribute__((ext_vector_type(4)));

__device__ inline unsigned short f2bf(float f) {
  unsigned u = __builtin_bit_cast(unsigned, f);
  u += 0x7fffu + ((u >> 16) & 1u);
  return (unsigned short)(u >> 16);
}
__device__ inline float fexp2(float x) {
#if __has_builtin(__builtin_amdgcn_exp2f)
  return __builtin_amdgcn_exp2f(x);
#else
  return exp2f(x);
#endif
}
__device__ inline float frcp(float x) {
#if __has_builtin(__builtin_amdgcn_rcpf)
  return __builtin_amdgcn_rcpf(x);
#else
  return 1.f / x;
#endif
}

// LDS-only barrier: flush LDS ops, sync execution, leave global loads in
// flight (no vmcnt drain); consumers get compiler-counted vmcnt waits.
__device__ inline void barrier_lds() {
  asm volatile("s_waitcnt lgkmcnt(0)\n\ts_barrier" ::: "memory");
}

// ---------------------------------------------------------------------------
// prep: weights fp32 -> bf16 with PER-GATE ARGUMENT PRE-SCALING:
//   gates i,f,o: scale by -log2(e)  = -1.44269504
//   gate  g    : scale by -2log2(e) = -2.88539008
// so sigm(x) = rcp(1+exp2(W'x)) and tanh(g) = 2*rcp(1+exp2(W'x)) - 1 need no
// in-kernel multiply. bsum = scale*(bih+bhh).
// ---------------------------------------------------------------------------
__global__ __launch_bounds__(256) void prep_weights(
    const float* __restrict__ Wih, const float* __restrict__ Whh,
    const float* __restrict__ bih, const float* __restrict__ bhh,
    unsigned short* __restrict__ WihB, unsigned short* __restrict__ WhhB,
    float* __restrict__ bsum) {
  int tid = blockIdx.x * 256 + threadIdx.x;  // 0..65535 float4 tasks
  int gate = ((tid >> 5) & 511) >> 7;
  float s = (gate == 2) ? -2.88539008f : -1.44269504f;
  float4 a = *(const float4*)(Wih + tid * 4);
  ushort4 o;
  o.x = f2bf(a.x * s); o.y = f2bf(a.y * s); o.z = f2bf(a.z * s); o.w = f2bf(a.w * s);
  *(ushort4*)(WihB + tid * 4) = o;
  float4 b = *(const float4*)(Whh + tid * 4);
  ushort4 p;
  p.x = f2bf(b.x * s); p.y = f2bf(b.y * s); p.z = f2bf(b.z * s); p.w = f2bf(b.w * s);
  *(ushort4*)(WhhB + tid * 4) = p;
  if (tid < 2048) {
    int g2 = (tid & 511) >> 7;
    float s2 = (g2 == 2) ? -2.88539008f : -1.44269504f;
    bsum[tid] = s2 * (bih[tid] + bhh[tid]);
  }
}

// ---------------------------------------------------------------------------
// cast: xbf = bf16(x)
// ---------------------------------------------------------------------------
__global__ __launch_bounds__(256) void cast_bf(
    const float* __restrict__ x, unsigned short* __restrict__ xb) {
  int tid = blockIdx.x * 256 + threadIdx.x;
  float4 v = *(const float4*)(x + tid * 4);
  ushort4 o;
  o.x = f2bf(v.x); o.y = f2bf(v.y); o.z = f2bf(v.z); o.w = f2bf(v.w);
  *(ushort4*)(xb + tid * 4) = o;
}

// ---------------------------------------------------------------------------
// lstm_fused: WG = 80 nodes, 8 waves; wave w owns gate-cols {g*128 + w*16+l15}.
// ---------------------------------------------------------------------------
__global__ __launch_bounds__(512, 2) void lstm_fused(
    const unsigned short* __restrict__ xbf,   // [N][128] bf16
    const int* __restrict__ src,              // [E]
    const unsigned short* __restrict__ WihB,  // [512][128] bf16 (layer slice)
    const unsigned short* __restrict__ WhhB,  // [512][128] bf16
    const float* __restrict__ bsum,           // [512]
    float* __restrict__ agg) {                // [N,128] fp32
  __shared__ __align__(16) unsigned char xsb[2][NPB * 256];   // x dbuf (40KB)
  __shared__ __align__(16) unsigned char hbuf[2][NPB * 256];  // h dbuf (40KB)
  __shared__ __align__(16) int idx_s[NPB * DEG];              // [t*80 + node]
  const int tid = threadIdx.x;
  const int lane = tid & 63, w = tid >> 6;
  const int l15 = lane & 15, l4 = lane >> 4;
  const int node0 = blockIdx.x * NPB;
  const int colb = w * 16 + l15;  // this wave-lane's output column (per gate)

  // edge indices: task = node*16 + t  ->  idx_s[t*80 + node]
#pragma unroll
  for (int i = 0; i < 3; ++i) {
    int task = tid + i * 512;
    if (task < NPB * DEG) {
      int node = task >> 4, t = task & 15;
      idx_s[t * NPB + node] = src[node0 * DEG + task];
    }
  }

  // weight B-fragments (bf16, pre-scaled): B[k][n] = W[gate*128+colb][k]
  bf16x8 bwx[4][4], bwh[4][4];
  float bs[4];
#pragma unroll
  for (int g = 0; g < 4; ++g) {
#pragma unroll
    for (int kt = 0; kt < 4; ++kt) {
      bwx[g][kt] = *(const bf16x8*)(WihB + (g * 128 + colb) * 128 + kt * 32 + l4 * 8);
      bwh[g][kt] = *(const bf16x8*)(WhhB + (g * 128 + colb) * 128 + kt * 32 + l4 * 8);
    }
    bs[g] = bsum[g * 128 + colb];
  }
  barrier_lds();  // idx_s visible

  // staging tasks: task = row*16 + chunk; LDS physical chunk p holds logical
  // chunk p ^ SWZ(row)  (matches the XOR-swizzled read below).
  const int task0 = tid, task1 = tid + 512;
  const int row0s = task0 >> 4, ch0 = task0 & 15;
  const int row1s = task1 >> 4, ch1 = task1 & 15;
  const int task2 = tid + 1024;
  const bool p2 = task2 < NPB * 16;
  const int row2s = task2 >> 4, ch2 = task2 & 15;

  // prologue: stage x rows for t=0
  {
    uint4 v0 = *(const uint4*)(xbf + idx_s[row0s] * 128 + (ch0 ^ SWZ(row0s)) * 8);
    uint4 v1 = *(const uint4*)(xbf + idx_s[row1s] * 128 + (ch1 ^ SWZ(row1s)) * 8);
    *(uint4*)(&xsb[0][row0s * 256 + ch0 * 16]) = v0;
    *(uint4*)(&xsb[0][row1s * 256 + ch1 * 16]) = v1;
    if (p2) {
      uint4 v2 = *(const uint4*)(xbf + idx_s[row2s] * 128 + (ch2 ^ SWZ(row2s)) * 8);
      *(uint4*)(&xsb[0][row2s * 256 + ch2 * 16]) = v2;
    }
  }
  barrier_lds();  // xsb[0] ready

  float c[RT][4];
#pragma unroll
  for (int rt = 0; rt < RT; ++rt)
#pragma unroll
    for (int r = 0; r < 4; ++r) c[rt][r] = 0.f;

#pragma unroll 2
  for (int t = 0; t < 16; ++t) {
    // (a) issue next step's x gather into regs (T14: write after compute)
    uint4 xstg0, xstg1, xstg2;
    if (t < 15) {
      const int tb = (t + 1) * NPB;
      xstg0 = *(const uint4*)(xbf + idx_s[tb + row0s] * 128 + (ch0 ^ SWZ(row0s)) * 8);
      xstg1 = *(const uint4*)(xbf + idx_s[tb + row1s] * 128 + (ch1 ^ SWZ(row1s)) * 8);
      if (p2)
        xstg2 = *(const uint4*)(xbf + idx_s[tb + row2s] * 128 + (ch2 ^ SWZ(row2s)) * 8);
    }

    const unsigned char* xrb = xsb[t & 1];
    const unsigned char* hb = hbuf[(t + 1) & 1];  // == (t-1)&1
    unsigned char* hw = hbuf[t & 1];

    // per-rt pipelined body: acc live only within one rt
#pragma unroll
    for (int rt = 0; rt < RT; ++rt) {
      f32x4 acc[4];
#pragma unroll
      for (int g = 0; g < 4; ++g) acc[g] = (f32x4){bs[g], bs[g], bs[g], bs[g]};

      const int m = rt * 16 + l15;
      // x-part (XOR on the FULL offset — mask bits overlap kt*64 at bit 6)
#pragma unroll
      for (int kt = 0; kt < 4; ++kt) {
        int byte = (m * 256 + kt * 64 + l4 * 16) ^ (SWZ(m) << 4);
        bf16x8 a = *(const bf16x8*)(xrb + byte);
#pragma unroll
        for (int g = 0; g < 4; ++g)
          acc[g] = __builtin_amdgcn_mfma_f32_16x16x32_bf16(a, bwx[g][kt], acc[g], 0, 0, 0);
      }
      // h-part (h == 0 at t==0)
      if (t > 0) {
#pragma unroll
        for (int kt = 0; kt < 4; ++kt) {
          int byte = (m * 256 + kt * 64 + l4 * 16) ^ (SWZ(m) << 4);
          bf16x8 a = *(const bf16x8*)(hb + byte);
#pragma unroll
          for (int g = 0; g < 4; ++g)
            acc[g] = __builtin_amdgcn_mfma_f32_16x16x32_bf16(a, bwh[g][kt], acc[g], 0, 0, 0);
        }
      }

      // gates + state update. Weights pre-scaled: acc = -1.4427*p (i,f,o),
      // -2.8854*p (g). sigm = rcp(1+exp2(acc)); tanh = 2*rcp(1+exp2(acc))-1.
#pragma unroll
      for (int r = 0; r < 4; ++r) {
        float ig = frcp(1.f + fexp2(acc[0][r]));
        float fg = frcp(1.f + fexp2(acc[1][r]));
        float gg = 2.f * frcp(1.f + fexp2(acc[2][r])) - 1.f;
        float og = frcp(1.f + fexp2(acc[3][r]));
        float cn = fg * c[rt][r] + ig * gg;
        c[rt][r] = cn;
        float th = 2.f * frcp(1.f + fexp2(-2.88539008f * cn)) - 1.f;
        float hv = og * th;
        int mm = rt * 16 + l4 * 4 + r;
        if (t < 15) {
          int byte = (mm * 256 + colb * 2) ^ (SWZ(mm) << 4);
          *(__bf16*)(hw + byte) = (__bf16)hv;
        } else {
          agg[(node0 + mm) * 128 + colb] = hv;
        }
      }
    }

    if (t < 15) {
      // write staged x for t+1 (linear; src was pre-swizzled)
      unsigned char* xw = xsb[(t + 1) & 1];
      *(uint4*)(&xw[row0s * 256 + ch0 * 16]) = xstg0;
      *(uint4*)(&xw[row1s * 256 + ch1 * 16]) = xstg1;
      if (p2) *(uint4*)(&xw[row2s * 256 + ch2 * 16]) = xstg2;
      barrier_lds();  // h_t and x_{t+1} visible; loads keep flying
    }
  }
}

// ---------------------------------------------------------------------------
// gemm_out: out[N,NOUT] = agg@Wl.T + bl + x@Wr.T (+resid) (+relu)
// One K=256 GEMM with A = [agg | x], B = [Wl | Wr]. Optionally dual-writes
// bf16 copy (next layer's gather source).
// ---------------------------------------------------------------------------
__global__ __launch_bounds__(256) void gemm_out(
    const float* __restrict__ A1,   // agg [N,128]
    const float* __restrict__ A2,   // x   [N,128]
    const float* __restrict__ Wl, const float* __restrict__ bl,
    const float* __restrict__ Wr,
    const float* __restrict__ resid,    // nullptr or [N,128]
    float* __restrict__ out,
    unsigned short* __restrict__ outbf,  // nullptr or [N,128] bf16
    int NOUT, int do_relu, int Nrows) {
  __shared__ __align__(16) unsigned char As[64 * 512];  // [64 rows][256 bf16], swizzled
  const int tid = threadIdx.x;
  const int lane = tid & 63, w = tid >> 6;
  const int l15 = lane & 15, l4 = lane >> 4;
  const int row0 = blockIdx.x * 64;

#pragma unroll
  for (int i = 0; i < 16; ++i) {
    int flat = i * 1024 + tid * 4;  // 0..16383
    int r = flat >> 8, c = flat & 255;
    int grow = row0 + r;
    float4 v;
    if (grow < Nrows)
      v = (c < 128) ? *(const float4*)(A1 + grow * 128 + c)
                    : *(const float4*)(A2 + grow * 128 + (c - 128));
    else
      v = make_float4(0.f, 0.f, 0.f, 0.f);
    ushort4 b;
    b.x = f2bf(v.x); b.y = f2bf(v.y); b.z = f2bf(v.z); b.w = f2bf(v.w);
    int byte = (r * 512 + c * 2) ^ ((r & 7) << 4);
    *(ushort4*)(As + byte) = b;
  }
  __syncthreads();

  const int colg = blockIdx.y * 64 + w * 16 + l15;
  bf16x8 bw[8];
#pragma unroll
  for (int kt = 0; kt < 8; ++kt) {
    const float* bp = (kt < 4) ? (Wl + colg * 128 + kt * 32 + l4 * 8)
                               : (Wr + colg * 128 + (kt - 4) * 32 + l4 * 8);
    float4 a = *(const float4*)bp;
    float4 b = *(const float4*)(bp + 4);
    bf16x8 v;
    v[0] = (__bf16)a.x; v[1] = (__bf16)a.y; v[2] = (__bf16)a.z; v[3] = (__bf16)a.w;
    v[4] = (__bf16)b.x; v[5] = (__bf16)b.y; v[6] = (__bf16)b.z; v[7] = (__bf16)b.w;
    bw[kt] = v;
  }

  f32x4 acc[4];
#pragma unroll
  for (int rt = 0; rt < 4; ++rt) acc[rt] = (f32x4){0.f, 0.f, 0.f, 0.f};

#pragma unroll
  for (int kt = 0; kt < 8; ++kt) {
#pragma unroll
    for (int rt = 0; rt < 4; ++rt) {
      int m = rt * 16 + l15;
      int byte = (m * 512 + kt * 64 + l4 * 16) ^ ((m & 7) << 4);
      bf16x8 af = *(const bf16x8*)(As + byte);
      acc[rt] = __builtin_amdgcn_mfma_f32_16x16x32_bf16(af, bw[kt], acc[rt], 0, 0, 0);
    }
  }

  const float bias = bl[colg];
#pragma unroll
  for (int rt = 0; rt < 4; ++rt)
#pragma unroll
    for (int r = 0; r < 4; ++r) {
      int grow = row0 + rt * 16 + l4 * 4 + r;
      if (grow < Nrows) {
        float v = acc[rt][r] + bias;
        if (resid) v += resid[grow * 128 + colg];
        if (do_relu) v = fmaxf(v, 0.f);
        out[grow * NOUT + colg] = v;
        if (outbf) outbf[grow * 128 + colg] = f2bf(v);
      }
    }
}

// ---------------------------------------------------------------------------
extern "C" void kernel_launch(void* const* d_in, const int* in_sizes, int n_in,
                              void* d_out, int out_size, void* d_ws, size_t ws_size,
                              hipStream_t stream) {
  const float* X = (const float*)d_in[0];
  const int* src = (const int*)d_in[1];  // edge_index[0] = first E ints
  const float* Wih = (const float*)d_in[2];
  const float* Whh = (const float*)d_in[3];
  const float* bih = (const float*)d_in[4];
  const float* bhh = (const float*)d_in[5];
  const float* Wl123 = (const float*)d_in[6];
  const float* bl123 = (const float*)d_in[7];
  const float* Wr123 = (const float*)d_in[8];
  const float* Wl4 = (const float*)d_in[9];
  const float* bl4 = (const float*)d_in[10];
  const float* Wr4 = (const float*)d_in[11];
  float* out = (float*)d_out;

  char* ws = (char*)d_ws;
  unsigned short* xbf = (unsigned short*)ws;                 // 5.12 MB
  float* agg = (float*)(ws + 5120000);                       // 10.24 MB
  float* xb0 = (float*)(ws + 15360000);                      // 10.24 MB
  float* xb1 = (float*)(ws + 25600000);                      // 10.24 MB
  unsigned short* WihB = (unsigned short*)(ws + 35840000);   // 0.52 MB
  unsigned short* WhhB = (unsigned short*)(ws + 36364288);   // 0.52 MB
  float* bsumW = (float*)(ws + 36888576);                    // 8 KB

  prep_weights<<<dim3(256), 256, 0, stream>>>(Wih, Whh, bih, bhh, WihB, WhhB, bsumW);
  cast_bf<<<dim3(2500), 256, 0, stream>>>(X, xbf);

  const float* xcur = X;
  for (int L = 0; L < 4; ++L) {
    lstm_fused<<<dim3(250), 512, 0, stream>>>(xbf, src, WihB + L * 65536,
                                              WhhB + L * 65536, bsumW + L * 512, agg);
    if (L < 3) {
      float* nxt = (L & 1) ? xb1 : xb0;
      gemm_out<<<dim3(313, 2), 256, 0, stream>>>(agg, xcur, Wl123 + L * 16384,
                                                 bl123 + L * 128, Wr123 + L * 16384,
                                                 (L >= 1) ? xcur : nullptr, nxt, xbf,
                                                 128, 1, N_NODES);
      xcur = nxt;
    } else {
      gemm_out<<<dim3(313, 1), 256, 0, stream>>>(agg, xcur, Wl4, bl4, Wr4, nullptr, out,
                                                 nullptr, 64, 0, N_NODES);
    }
  }
}